// Round 1
// baseline (372.555 us; speedup 1.0000x reference)
//
#include <hip/hip_runtime.h>
#include <cstdint>
#include <cstddef>

// Problem constants
#define B_  16
#define C_  384
#define H_  48
#define W_  48
#define HW_ 2304        // 48*48
#define KP_ 9           // K*K

// ---------------------------------------------------------------------------
// Kernel 1: per-(b,c) 3x3 adaptive average pool (16x16 blocks) + global mean.
// px[b,c,p], p = ih*3+iw (block means); emb[b,c] = plane mean.
// ---------------------------------------------------------------------------
__global__ void pool_kernel(const float* __restrict__ x,
                            float* __restrict__ px, float* __restrict__ emb) {
    const int bc = blockIdx.x;                 // b*384 + c
    const float* xp = x + (size_t)bc * HW_;
    const int t = threadIdx.x;                 // 256 threads
    __shared__ float red[4];

    float v[9];
#pragma unroll
    for (int r = 0; r < 9; ++r) {
        const int ri = r / 3, rj = r % 3;
        const int h = ri * 16 + (t >> 4);
        const int w = rj * 16 + (t & 15);
        v[r] = xp[h * W_ + w];
    }
    float total = 0.f;
#pragma unroll
    for (int r = 0; r < 9; ++r) {
        float s = v[r];
#pragma unroll
        for (int o = 32; o > 0; o >>= 1) s += __shfl_down(s, o);
        if ((t & 63) == 0) red[t >> 6] = s;
        __syncthreads();
        if (t == 0) {
            const float bs = red[0] + red[1] + red[2] + red[3];
            px[bc * 9 + r] = bs * (1.f / 256.f);
            total += bs;
        }
        __syncthreads();
    }
    if (t == 0) emb[bc] = total * (1.f / 2304.f);
}

// ---------------------------------------------------------------------------
// Kernel 2: small projections.
//  qk[b,o,p]   = bq[o] + sum_i Wq[o,i] px[b,i,p]
//  kf[b,o,q]   = bg[q] + sum_p qk[b,o,p] Wg[q,p]
//  k[b,o]      = bk[o] + sum_i Wk[o,i] emb[b,i]
//  kern[b,o,q] = kf - sigmoid(k) * mean_q(kf)
// grid (3, 16), block 128: thread owns one output channel o.
// ---------------------------------------------------------------------------
__global__ void small_kernel(const float* __restrict__ px, const float* __restrict__ emb,
                             const float* __restrict__ Wq, const float* __restrict__ bq,
                             const float* __restrict__ Wk, const float* __restrict__ bk,
                             const float* __restrict__ Wg, const float* __restrict__ bg,
                             float* __restrict__ kern) {
    const int b = blockIdx.y;
    const int o = blockIdx.x * 128 + threadIdx.x;

    __shared__ float px_l[C_ * 9];
    __shared__ float emb_l[C_];
    __shared__ float wg_l[81];
    __shared__ float bg_l[9];

    for (int idx = threadIdx.x; idx < C_ * 9; idx += 128) px_l[idx] = px[(size_t)b * C_ * 9 + idx];
    for (int idx = threadIdx.x; idx < C_;     idx += 128) emb_l[idx] = emb[(size_t)b * C_ + idx];
    if (threadIdx.x < 81) wg_l[threadIdx.x] = Wg[threadIdx.x];
    if (threadIdx.x < 9)  bg_l[threadIdx.x] = bg[threadIdx.x];
    __syncthreads();

    float accq[9];
#pragma unroll
    for (int p = 0; p < 9; ++p) accq[p] = bq[o];
    float acck = bk[o];
    const float* wq_row = Wq + (size_t)o * C_;
    const float* wk_row = Wk + (size_t)o * C_;
    for (int i = 0; i < C_; ++i) {
        const float w = wq_row[i];
#pragma unroll
        for (int p = 0; p < 9; ++p) accq[p] = fmaf(w, px_l[i * 9 + p], accq[p]);
        acck = fmaf(wk_row[i], emb_l[i], acck);
    }

    float kf[9];
    float mean = 0.f;
#pragma unroll
    for (int q = 0; q < 9; ++q) {
        float a = bg_l[q];
#pragma unroll
        for (int p = 0; p < 9; ++p) a = fmaf(accq[p], wg_l[q * 9 + p], a);
        kf[q] = a;
        mean += a;
    }
    mean *= (1.f / 9.f);
    const float sig = 1.f / (1.f + expf(-acck));

    float* kout = kern + ((size_t)b * C_ + o) * 9;
#pragma unroll
    for (int q = 0; q < 9; ++q) kout[q] = kf[q] - sig * mean;
}

// ---------------------------------------------------------------------------
// Kernel 3/5: fp32 1x1-conv GEMM.  Y[b,m,n] = bias[m] + sum_k W[m,k] X[b,k,n]
// 64x64 tile, K-step 16, 256 threads, 4x4 microtile per thread.
// grid (36, 6, 16).
// ---------------------------------------------------------------------------
__global__ void conv1x1_gemm(const float* __restrict__ X, const float* __restrict__ W,
                             const float* __restrict__ bias, float* __restrict__ Y) {
    const int n0 = blockIdx.x * 64;
    const int m0 = blockIdx.y * 64;
    const int b  = blockIdx.z;
    const int t  = threadIdx.x;
    const int tx = t & 15, ty = t >> 4;

    __shared__ float As[16][64];   // As[k][m]
    __shared__ float Bs[16][64];   // Bs[k][n]

    float acc[4][4] = {};
    const float* Xb = X + (size_t)b * C_ * HW_;

    for (int k0 = 0; k0 < C_; k0 += 16) {
        {   // A tile: W[m0+mm][k0+kk..kk+3] -> transposed store
            const int mm = t >> 2, kk = (t & 3) * 4;
            const float4 w4 = *(const float4*)&W[(size_t)(m0 + mm) * C_ + k0 + kk];
            As[kk + 0][mm] = w4.x; As[kk + 1][mm] = w4.y;
            As[kk + 2][mm] = w4.z; As[kk + 3][mm] = w4.w;
        }
        {   // B tile: X[b][k0+kk][n0+nn..nn+3]
            const int kk = t >> 4, nn = (t & 15) * 4;
            *(float4*)&Bs[kk][nn] = *(const float4*)&Xb[(size_t)(k0 + kk) * HW_ + n0 + nn];
        }
        __syncthreads();
#pragma unroll
        for (int k = 0; k < 16; ++k) {
            const float4 a4 = *(const float4*)&As[k][ty * 4];
            const float4 b4 = *(const float4*)&Bs[k][tx * 4];
            const float av[4] = {a4.x, a4.y, a4.z, a4.w};
            const float bv[4] = {b4.x, b4.y, b4.z, b4.w};
#pragma unroll
            for (int im = 0; im < 4; ++im)
#pragma unroll
                for (int in = 0; in < 4; ++in)
                    acc[im][in] = fmaf(av[im], bv[in], acc[im][in]);
        }
        __syncthreads();
    }

#pragma unroll
    for (int im = 0; im < 4; ++im) {
        const int m = m0 + ty * 4 + im;
        const float bsv = bias[m];
        float4 o4;
        o4.x = acc[im][0] + bsv; o4.y = acc[im][1] + bsv;
        o4.z = acc[im][2] + bsv; o4.w = acc[im][3] + bsv;
        *(float4*)&Y[((size_t)b * C_ + m) * HW_ + n0 + tx * 4] = o4;
    }
}

// ---------------------------------------------------------------------------
// Kernel 4: dynamic depthwise 3x3, in-place on V (per-(b,c) plane staged to
// LDS with zero halo first, so in-place is race-free).
// ---------------------------------------------------------------------------
__global__ void dw_kernel(float* __restrict__ V, const float* __restrict__ kern) {
    const int bc = blockIdx.x;
    float* vp = V + (size_t)bc * HW_;
    const int t = threadIdx.x;     // 256

    __shared__ float pl[50 * 50];
    __shared__ float kl[9];

    for (int idx = t; idx < 2500; idx += 256) pl[idx] = 0.f;
    __syncthreads();
    if (t < 9) kl[t] = kern[(size_t)bc * 9 + t];
    for (int p = t; p < HW_; p += 256) {
        const int h = p / W_, w = p % W_;
        pl[(h + 1) * 50 + (w + 1)] = vp[p];
    }
    __syncthreads();

    const float k0 = kl[0], k1 = kl[1], k2 = kl[2];
    const float k3 = kl[3], k4 = kl[4], k5 = kl[5];
    const float k6 = kl[6], k7 = kl[7], k8 = kl[8];

    for (int p = t; p < HW_; p += 256) {
        const int h = p / W_, w = p % W_;
        const float* r0 = &pl[h * 50 + w];
        const float acc = k0 * r0[0]   + k1 * r0[1]   + k2 * r0[2]
                        + k3 * r0[50]  + k4 * r0[51]  + k5 * r0[52]
                        + k6 * r0[100] + k7 * r0[101] + k8 * r0[102];
        vp[p] = acc;
    }
}

// ---------------------------------------------------------------------------
extern "C" void kernel_launch(void* const* d_in, const int* in_sizes, int n_in,
                              void* d_out, int out_size, void* d_ws, size_t ws_size,
                              hipStream_t stream) {
    const float* x  = (const float*)d_in[0];
    const float* Wq = (const float*)d_in[1];
    const float* bq = (const float*)d_in[2];
    const float* Wk = (const float*)d_in[3];
    const float* bk = (const float*)d_in[4];
    const float* Wv = (const float*)d_in[5];
    const float* bv = (const float*)d_in[6];
    const float* Wg = (const float*)d_in[7];
    const float* bg = (const float*)d_in[8];
    const float* Wp = (const float*)d_in[9];
    const float* bp = (const float*)d_in[10];
    float* out = (float*)d_out;

    char* ws = (char*)d_ws;
    const size_t value_bytes = (size_t)B_ * C_ * HW_ * sizeof(float);   // 56,623,104
    float* value = (float*)ws;
    float* px    = (float*)(ws + value_bytes);
    float* emb   = (float*)(ws + value_bytes + 221184);
    float* kern  = (float*)(ws + value_bytes + 221184 + 24576);

    // 1. pooled x (B,C,9) + global mean (B,C)
    pool_kernel<<<B_ * C_, 256, 0, stream>>>(x, px, emb);
    // 2. dynamic kernels (B,C,9)
    small_kernel<<<dim3(3, B_), 128, 0, stream>>>(px, emb, Wq, bq, Wk, bk, Wg, bg, kern);
    // 3. value = Wv * x + bv
    conv1x1_gemm<<<dim3(HW_ / 64, C_ / 64, B_), 256, 0, stream>>>(x, Wv, bv, value);
    // 4. depthwise dynamic 3x3 (in-place on value)
    dw_kernel<<<B_ * C_, 256, 0, stream>>>(value, kern);
    // 5. out = Wp * value + bp
    conv1x1_gemm<<<dim3(HW_ / 64, C_ / 64, B_), 256, 0, stream>>>(value, Wp, bp, out);
}

// Round 2
// 177.482 us; speedup vs baseline: 2.0991x; 2.0991x over previous
//
#include <hip/hip_runtime.h>
#include <cstdint>
#include <cstddef>

// Problem constants
#define B_  16
#define C_  384
#define H_  48
#define W_  48
#define HW_ 2304        // 48*48

typedef __bf16 bf16x8 __attribute__((ext_vector_type(8)));
typedef float  f32x4  __attribute__((ext_vector_type(4)));
typedef unsigned short u16x8 __attribute__((ext_vector_type(8)));

typedef __attribute__((address_space(3))) void       lds_void;
typedef const __attribute__((address_space(1))) void gbl_void;

__device__ __forceinline__ unsigned short f2bf(float f) {
    union { float f; unsigned int u; } v; v.f = f;
    unsigned int r = v.u + 0x7fffu + ((v.u >> 16) & 1u);   // RNE
    return (unsigned short)(r >> 16);
}
__device__ __forceinline__ float bf2f(unsigned short u) {
    union { unsigned int u; float f; } v; v.u = ((unsigned int)u) << 16;
    return v.f;
}

// ---------------------------------------------------------------------------
// cast fp32 -> bf16 bits (weights)
// ---------------------------------------------------------------------------
__global__ void castw_kernel(const float* __restrict__ s, unsigned short* __restrict__ d, int n) {
    const int i = (blockIdx.x * 256 + threadIdx.x) * 4;
    if (i + 3 < n) {
        const float4 v = *(const float4*)&s[i];
        ushort4 o; o.x = f2bf(v.x); o.y = f2bf(v.y); o.z = f2bf(v.z); o.w = f2bf(v.w);
        *(ushort4*)&d[i] = o;
    }
}

// ---------------------------------------------------------------------------
// transpose-cast: x[b][c][p] fp32 -> xT[b][p][c] bf16.  64x64 tiles via LDS.
// grid (36, 6, 16), block 256.
// ---------------------------------------------------------------------------
__global__ __launch_bounds__(256) void tcast_kernel(const float* __restrict__ x,
                                                    unsigned short* __restrict__ xT) {
    __shared__ unsigned short tile[64][68];   // [p][c], padded stride 136B
    const int t  = threadIdx.x;
    const int b  = blockIdx.z;
    const int p0 = blockIdx.x * 64, c0 = blockIdx.y * 64;
    const float* xb = x + ((size_t)b * C_ + c0) * HW_ + p0;

#pragma unroll
    for (int pass = 0; pass < 4; ++pass) {
        const int cr = pass * 16 + (t >> 4);
        const int pc = (t & 15) * 4;
        const float4 v = *(const float4*)&xb[(size_t)cr * HW_ + pc];
        tile[pc + 0][cr] = f2bf(v.x); tile[pc + 1][cr] = f2bf(v.y);
        tile[pc + 2][cr] = f2bf(v.z); tile[pc + 3][cr] = f2bf(v.w);
    }
    __syncthreads();
    unsigned short* xTb = xT + ((size_t)b * HW_ + p0) * C_ + c0;
#pragma unroll
    for (int pass = 0; pass < 4; ++pass) {
        const int pr = pass * 16 + (t >> 4);
        const int cc = (t & 15) * 4;
        *(ushort4*)&xTb[(size_t)pr * C_ + cc] = *(const ushort4*)&tile[pr][cc];
    }
}

// ---------------------------------------------------------------------------
// pool: per-(b,c) 3x3 adaptive avg pool + global mean (unchanged, passed R1)
// ---------------------------------------------------------------------------
__global__ void pool_kernel(const float* __restrict__ x,
                            float* __restrict__ px, float* __restrict__ emb) {
    const int bc = blockIdx.x;
    const float* xp = x + (size_t)bc * HW_;
    const int t = threadIdx.x;
    __shared__ float red[4];

    float v[9];
#pragma unroll
    for (int r = 0; r < 9; ++r) {
        const int ri = r / 3, rj = r % 3;
        v[r] = xp[(ri * 16 + (t >> 4)) * W_ + rj * 16 + (t & 15)];
    }
    float total = 0.f;
#pragma unroll
    for (int r = 0; r < 9; ++r) {
        float s = v[r];
#pragma unroll
        for (int o = 32; o > 0; o >>= 1) s += __shfl_down(s, o);
        if ((t & 63) == 0) red[t >> 6] = s;
        __syncthreads();
        if (t == 0) {
            const float bs = red[0] + red[1] + red[2] + red[3];
            px[bc * 9 + r] = bs * (1.f / 256.f);
            total += bs;
        }
        __syncthreads();
    }
    if (t == 0) emb[bc] = total * (1.f / 2304.f);
}

// ---------------------------------------------------------------------------
// small projections -> kernT[b][q][c] bf16
// ---------------------------------------------------------------------------
__global__ void small_kernel(const float* __restrict__ px, const float* __restrict__ emb,
                             const float* __restrict__ Wq, const float* __restrict__ bq,
                             const float* __restrict__ Wk, const float* __restrict__ bk,
                             const float* __restrict__ Wg, const float* __restrict__ bg,
                             unsigned short* __restrict__ kernT) {
    const int b = blockIdx.y;
    const int o = blockIdx.x * 128 + threadIdx.x;

    __shared__ float px_l[C_ * 9];
    __shared__ float emb_l[C_];
    __shared__ float wg_l[81];
    __shared__ float bg_l[9];

    for (int idx = threadIdx.x; idx < C_ * 9; idx += 128) px_l[idx] = px[(size_t)b * C_ * 9 + idx];
    for (int idx = threadIdx.x; idx < C_;     idx += 128) emb_l[idx] = emb[(size_t)b * C_ + idx];
    if (threadIdx.x < 81) wg_l[threadIdx.x] = Wg[threadIdx.x];
    if (threadIdx.x < 9)  bg_l[threadIdx.x] = bg[threadIdx.x];
    __syncthreads();

    float accq[9];
#pragma unroll
    for (int p = 0; p < 9; ++p) accq[p] = bq[o];
    float acck = bk[o];
    const float* wq_row = Wq + (size_t)o * C_;
    const float* wk_row = Wk + (size_t)o * C_;
    for (int i = 0; i < C_; ++i) {
        const float w = wq_row[i];
#pragma unroll
        for (int p = 0; p < 9; ++p) accq[p] = fmaf(w, px_l[i * 9 + p], accq[p]);
        acck = fmaf(wk_row[i], emb_l[i], acck);
    }

    float kf[9], mean = 0.f;
#pragma unroll
    for (int q = 0; q < 9; ++q) {
        float a = bg_l[q];
#pragma unroll
        for (int p = 0; p < 9; ++p) a = fmaf(accq[p], wg_l[q * 9 + p], a);
        kf[q] = a; mean += a;
    }
    mean *= (1.f / 9.f);
    const float sig = 1.f / (1.f + expf(-acck));
#pragma unroll
    for (int q = 0; q < 9; ++q)
        kernT[((size_t)b * 9 + q) * C_ + o] = f2bf(kf[q] - sig * mean);
}

// ---------------------------------------------------------------------------
// bf16 MFMA GEMM (m97 structure): D[m][n] = sum_k A[m][k]*Bt[n][k] + bias
// A: [M][384] bf16 row-major, Bt: [N][384] bf16 row-major.
// 128x128 tile, 4 waves each 64x64 (4x4 frags of 16x16), BK=32.
// BIAS_COL: bias indexed by col (else by row). OUT_BF16: store bf16 bits.
// ---------------------------------------------------------------------------
template<int BIAS_COL, bool OUT_BF16>
__global__ __launch_bounds__(256) void gemm_bt(const unsigned short* __restrict__ A,
                                               const unsigned short* __restrict__ Bt,
                                               const float* __restrict__ bias,
                                               void* __restrict__ Yv,
                                               int M, int N,
                                               long long sA, long long sB, long long sY) {
    const int t = threadIdx.x;
    const int l = t & 63, w = t >> 6;
    const int m0 = blockIdx.y * 128, n0 = blockIdx.x * 128;
    const int b  = blockIdx.z;
    const unsigned short* Ab = A + (size_t)b * sA;
    const unsigned short* Bb = Bt + (size_t)b * sB;

    __shared__ __align__(16) unsigned short As[128 * 32];
    __shared__ __align__(16) unsigned short Bs[128 * 32];

    f32x4 acc[4][4] = {};
    const int wm = w >> 1, wn = w & 1;
    const int srow = t >> 2;            // staging row 0..63
    const int skc  = (t & 3) * 8;       // staging k-offset (elements)

    for (int k0 = 0; k0 < 384; k0 += 32) {
        __builtin_amdgcn_global_load_lds(
            (gbl_void*)(Ab + (size_t)(m0 + srow) * 384 + k0 + skc),
            (lds_void*)(As + t * 8), 16, 0, 0);
        __builtin_amdgcn_global_load_lds(
            (gbl_void*)(Ab + (size_t)(m0 + 64 + srow) * 384 + k0 + skc),
            (lds_void*)(As + 2048 + t * 8), 16, 0, 0);
        __builtin_amdgcn_global_load_lds(
            (gbl_void*)(Bb + (size_t)(n0 + srow) * 384 + k0 + skc),
            (lds_void*)(Bs + t * 8), 16, 0, 0);
        __builtin_amdgcn_global_load_lds(
            (gbl_void*)(Bb + (size_t)(n0 + 64 + srow) * 384 + k0 + skc),
            (lds_void*)(Bs + 2048 + t * 8), 16, 0, 0);
        __syncthreads();   // drains vmcnt(0) then barrier

        const int lr = l & 15, lk = (l >> 4) * 8;
        bf16x8 af[4], bfr[4];
#pragma unroll
        for (int f = 0; f < 4; ++f)
            af[f] = *reinterpret_cast<const bf16x8*>(&As[(wm * 64 + f * 16 + lr) * 32 + lk]);
#pragma unroll
        for (int f = 0; f < 4; ++f)
            bfr[f] = *reinterpret_cast<const bf16x8*>(&Bs[(wn * 64 + f * 16 + lr) * 32 + lk]);
#pragma unroll
        for (int fm = 0; fm < 4; ++fm)
#pragma unroll
            for (int fn = 0; fn < 4; ++fn)
                acc[fm][fn] = __builtin_amdgcn_mfma_f32_16x16x32_bf16(af[fm], bfr[fn], acc[fm][fn], 0, 0, 0);
        __syncthreads();   // protect LDS reuse next step
    }

    // epilogue: D row = (l>>4)*4 + r, col = l&15 (m89-verified layout)
    const int lr = l & 15, lg = (l >> 4) * 4;
#pragma unroll
    for (int fm = 0; fm < 4; ++fm) {
        const int row = m0 + wm * 64 + fm * 16 + lg;
#pragma unroll
        for (int fn = 0; fn < 4; ++fn) {
            const int col = n0 + wn * 64 + fn * 16 + lr;
            const float cb = BIAS_COL ? bias[col] : 0.f;
#pragma unroll
            for (int r = 0; r < 4; ++r) {
                const float v = acc[fm][fn][r] + (BIAS_COL ? cb : bias[row + r]);
                if (OUT_BF16)
                    ((unsigned short*)Yv)[(size_t)b * sY + (size_t)(row + r) * N + col] = f2bf(v);
                else
                    ((float*)Yv)[(size_t)b * sY + (size_t)(row + r) * N + col] = v;
            }
        }
    }
}

// ---------------------------------------------------------------------------
// depthwise dynamic 3x3 in channel-last space:
// oT[b][p][c] = sum_q vT[b][p+delta(q)][c] * kT[b][q][c]   (zero-padded)
// grid (8 strips of 6 rows, 2 c-halves, 16 b), block (24, 16) = 384 thr.
// ---------------------------------------------------------------------------
__global__ __launch_bounds__(384) void dwT_kernel(const unsigned short* __restrict__ vT,
                                                  const unsigned short* __restrict__ kT,
                                                  unsigned short* __restrict__ oT) {
    const int b  = blockIdx.z;
    const int hs = blockIdx.x;
    const int c0 = (blockIdx.y * 24 + threadIdx.x) * 8;
    const size_t base = (size_t)b * HW_ * C_;

    float kf[9][8];
#pragma unroll
    for (int q = 0; q < 9; ++q) {
        const u16x8 kv = *(const u16x8*)&kT[((size_t)b * 9 + q) * C_ + c0];
#pragma unroll
        for (int e = 0; e < 8; ++e) kf[q][e] = bf2f(kv[e]);
    }

    for (int pi = threadIdx.y; pi < 288; pi += 16) {
        const int r = pi / 48, ww = pi % 48;
        const int h = hs * 6 + r;
        float acc[8] = {0.f, 0.f, 0.f, 0.f, 0.f, 0.f, 0.f, 0.f};
#pragma unroll
        for (int di = 0; di < 3; ++di) {
            const int hh = h + di - 1;
            if (hh < 0 || hh >= H_) continue;
#pragma unroll
            for (int dj = 0; dj < 3; ++dj) {
                const int wn = ww + dj - 1;
                if (wn < 0 || wn >= W_) continue;
                const u16x8 v = *(const u16x8*)&vT[base + (size_t)(hh * W_ + wn) * C_ + c0];
                const int q = di * 3 + dj;
#pragma unroll
                for (int e = 0; e < 8; ++e) acc[e] = fmaf(bf2f(v[e]), kf[q][e], acc[e]);
            }
        }
        u16x8 o;
#pragma unroll
        for (int e = 0; e < 8; ++e) o[e] = f2bf(acc[e]);
        *(u16x8*)&oT[base + (size_t)(h * W_ + ww) * C_ + c0] = o;
    }
}

// ---------------------------------------------------------------------------
extern "C" void kernel_launch(void* const* d_in, const int* in_sizes, int n_in,
                              void* d_out, int out_size, void* d_ws, size_t ws_size,
                              hipStream_t stream) {
    const float* x  = (const float*)d_in[0];
    const float* Wq = (const float*)d_in[1];
    const float* bq = (const float*)d_in[2];
    const float* Wk = (const float*)d_in[3];
    const float* bk = (const float*)d_in[4];
    const float* Wv = (const float*)d_in[5];
    const float* bv = (const float*)d_in[6];
    const float* Wg = (const float*)d_in[7];
    const float* bg = (const float*)d_in[8];
    const float* Wp = (const float*)d_in[9];
    const float* bp = (const float*)d_in[10];
    float* out = (float*)d_out;

    char* ws = (char*)d_ws;
    const size_t bhwc2 = (size_t)B_ * HW_ * C_ * 2;          // 28,311,552 B
    unsigned short* xT     = (unsigned short*)ws;             // also reused as out2T
    unsigned short* valueT = (unsigned short*)(ws + bhwc2);
    unsigned short* Wvb    = (unsigned short*)(ws + 2 * bhwc2);
    unsigned short* Wpb    = (unsigned short*)(ws + 2 * bhwc2 + 294912);
    float*          px     = (float*)(ws + 2 * bhwc2 + 2 * 294912);
    float*          emb    = (float*)(ws + 2 * bhwc2 + 2 * 294912 + 221184);
    unsigned short* kernT  = (unsigned short*)(ws + 2 * bhwc2 + 2 * 294912 + 221184 + 24576);
    unsigned short* out2T  = xT;   // xT dead after GEMM1

    castw_kernel<<<144, 256, 0, stream>>>(Wv, Wvb, C_ * C_);
    castw_kernel<<<144, 256, 0, stream>>>(Wp, Wpb, C_ * C_);
    tcast_kernel<<<dim3(HW_ / 64, C_ / 64, B_), 256, 0, stream>>>(x, xT);
    pool_kernel<<<B_ * C_, 256, 0, stream>>>(x, px, emb);
    small_kernel<<<dim3(3, B_), 128, 0, stream>>>(px, emb, Wq, bq, Wk, bk, Wg, bg, kernT);

    // valueT[b][p][c] = xT[b][p][:] . Wv[c][:] + bv[c]   (bias per col, bf16 out)
    gemm_bt<1, true><<<dim3(C_ / 128, HW_ / 128, B_), 256, 0, stream>>>(
        xT, Wvb, bv, (void*)valueT, HW_, C_,
        (long long)HW_ * C_, 0LL, (long long)HW_ * C_);

    dwT_kernel<<<dim3(8, 2, B_), dim3(24, 16), 0, stream>>>(valueT, kernT, out2T);

    // out[b][c][p] = Wp[c][:] . out2T[b][p][:] + bp[c]   (bias per row, fp32 out)
    gemm_bt<0, false><<<dim3(HW_ / 128, C_ / 128, B_), 256, 0, stream>>>(
        Wpb, out2T, bp, (void*)out, C_, HW_,
        0LL, (long long)HW_ * C_, (long long)C_ * HW_);
}

// Round 3
// 137.832 us; speedup vs baseline: 2.7030x; 1.2877x over previous
//
#include <hip/hip_runtime.h>
#include <cstdint>
#include <cstddef>

// Problem constants
#define B_  16
#define C_  384
#define H_  48
#define W_  48
#define HW_ 2304        // 48*48

typedef __bf16 bf16x8 __attribute__((ext_vector_type(8)));
typedef float  f32x4  __attribute__((ext_vector_type(4)));
typedef unsigned short u16x8 __attribute__((ext_vector_type(8)));

typedef __attribute__((address_space(3))) void       lds_void;
typedef const __attribute__((address_space(1))) void gbl_void;

__device__ __forceinline__ unsigned short f2bf(float f) {
    union { float f; unsigned int u; } v; v.f = f;
    unsigned int r = v.u + 0x7fffu + ((v.u >> 16) & 1u);   // RNE
    return (unsigned short)(r >> 16);
}
__device__ __forceinline__ float bf2f(unsigned short u) {
    union { unsigned int u; float f; } v; v.u = ((unsigned int)u) << 16;
    return v.f;
}

// ---------------------------------------------------------------------------
// cast fp32 -> bf16 bits (weights)
// ---------------------------------------------------------------------------
__global__ void castw_kernel(const float* __restrict__ s, unsigned short* __restrict__ d, int n) {
    const int i = (blockIdx.x * 256 + threadIdx.x) * 4;
    if (i + 3 < n) {
        const float4 v = *(const float4*)&s[i];
        ushort4 o; o.x = f2bf(v.x); o.y = f2bf(v.y); o.z = f2bf(v.z); o.w = f2bf(v.w);
        *(ushort4*)&d[i] = o;
    }
}

// ---------------------------------------------------------------------------
// transpose-cast: x[b][c][p] fp32 -> xT[b][p][c] bf16.  64x64 tiles via LDS.
// grid (36, 6, 16), block 256.
// ---------------------------------------------------------------------------
__global__ __launch_bounds__(256) void tcast_kernel(const float* __restrict__ x,
                                                    unsigned short* __restrict__ xT) {
    __shared__ unsigned short tile[64][68];   // [p][c], padded
    const int t  = threadIdx.x;
    const int b  = blockIdx.z;
    const int p0 = blockIdx.x * 64, c0 = blockIdx.y * 64;
    const float* xb = x + ((size_t)b * C_ + c0) * HW_ + p0;

#pragma unroll
    for (int pass = 0; pass < 4; ++pass) {
        const int cr = pass * 16 + (t >> 4);
        const int pc = (t & 15) * 4;
        const float4 v = *(const float4*)&xb[(size_t)cr * HW_ + pc];
        tile[pc + 0][cr] = f2bf(v.x); tile[pc + 1][cr] = f2bf(v.y);
        tile[pc + 2][cr] = f2bf(v.z); tile[pc + 3][cr] = f2bf(v.w);
    }
    __syncthreads();
    unsigned short* xTb = xT + ((size_t)b * HW_ + p0) * C_ + c0;
#pragma unroll
    for (int pass = 0; pass < 4; ++pass) {
        const int pr = pass * 16 + (t >> 4);
        const int cc = (t & 15) * 4;
        *(ushort4*)&xTb[(size_t)pr * C_ + cc] = *(const ushort4*)&tile[pr][cc];
    }
}

// ---------------------------------------------------------------------------
// poolT: 3x3 adaptive avg pool from xT (bf16, channel-last).
// px[b][c][r], r = ri*3+rj.  grid (9, 6, 16), block 256 (4 waves).
// Wave w handles pixels w*64..w*64+63 of the 16x16 block; lane = i*8+cg.
// ---------------------------------------------------------------------------
__global__ __launch_bounds__(256) void poolT_kernel(const unsigned short* __restrict__ xT,
                                                    float* __restrict__ px) {
    const int r  = blockIdx.x;           // 0..8
    const int c0 = blockIdx.y * 64;
    const int b  = blockIdx.z;
    const int t  = threadIdx.x;
    const int wv = t >> 6;               // wave 0..3
    const int l  = t & 63;
    const int i  = l >> 3;               // 0..7 pixel-slot
    const int cg = l & 7;                // 0..7 channel-group
    const int ri = r / 3, rj = r % 3;
    const int cbase = c0 + cg * 8;

    __shared__ float s[4][64];

    float acc[8] = {};
#pragma unroll
    for (int k = 0; k < 8; ++k) {
        const int pix = wv * 64 + i + k * 8;
        const int h = ri * 16 + (pix >> 4), w = rj * 16 + (pix & 15);
        const u16x8 v = *(const u16x8*)&xT[((size_t)b * HW_ + h * W_ + w) * C_ + cbase];
#pragma unroll
        for (int e = 0; e < 8; ++e) acc[e] += bf2f(v[e]);
    }
    // reduce over i (lane bits 3,4,5)
#pragma unroll
    for (int m = 8; m <= 32; m <<= 1)
#pragma unroll
        for (int e = 0; e < 8; ++e) acc[e] += __shfl_xor(acc[e], m, 64);
    if (i == 0)
#pragma unroll
        for (int e = 0; e < 8; ++e) s[wv][cg * 8 + e] = acc[e];
    __syncthreads();
    if (t < 64) {
        const float tot = s[0][t] + s[1][t] + s[2][t] + s[3][t];
        px[((size_t)b * C_ + c0 + t) * 9 + r] = tot * (1.f / 256.f);
    }
}

// ---------------------------------------------------------------------------
// small projections -> kernT[b][q][c] bf16.  emb derived from px (mean of the
// 9 equal-block means == plane mean).
// ---------------------------------------------------------------------------
__global__ void small_kernel(const float* __restrict__ px,
                             const float* __restrict__ Wq, const float* __restrict__ bq,
                             const float* __restrict__ Wk, const float* __restrict__ bk,
                             const float* __restrict__ Wg, const float* __restrict__ bg,
                             unsigned short* __restrict__ kernT) {
    const int b = blockIdx.y;
    const int o = blockIdx.x * 128 + threadIdx.x;

    __shared__ float px_l[C_ * 9];
    __shared__ float emb_l[C_];
    __shared__ float wg_l[81];
    __shared__ float bg_l[9];

    for (int idx = threadIdx.x; idx < C_ * 9; idx += 128) px_l[idx] = px[(size_t)b * C_ * 9 + idx];
    if (threadIdx.x < 81) wg_l[threadIdx.x] = Wg[threadIdx.x];
    if (threadIdx.x < 9)  bg_l[threadIdx.x] = bg[threadIdx.x];
    __syncthreads();
    for (int idx = threadIdx.x; idx < C_; idx += 128) {
        float s0 = 0.f;
#pragma unroll
        for (int p = 0; p < 9; ++p) s0 += px_l[idx * 9 + p];
        emb_l[idx] = s0 * (1.f / 9.f);
    }
    __syncthreads();

    float accq[9];
#pragma unroll
    for (int p = 0; p < 9; ++p) accq[p] = bq[o];
    float acck = bk[o];
    const float* wq_row = Wq + (size_t)o * C_;
    const float* wk_row = Wk + (size_t)o * C_;
    for (int i = 0; i < C_; ++i) {
        const float w = wq_row[i];
#pragma unroll
        for (int p = 0; p < 9; ++p) accq[p] = fmaf(w, px_l[i * 9 + p], accq[p]);
        acck = fmaf(wk_row[i], emb_l[i], acck);
    }

    float kf[9], mean = 0.f;
#pragma unroll
    for (int q = 0; q < 9; ++q) {
        float a = bg_l[q];
#pragma unroll
        for (int p = 0; p < 9; ++p) a = fmaf(accq[p], wg_l[q * 9 + p], a);
        kf[q] = a; mean += a;
    }
    mean *= (1.f / 9.f);
    const float sig = 1.f / (1.f + expf(-acck));
#pragma unroll
    for (int q = 0; q < 9; ++q)
        kernT[((size_t)b * 9 + q) * C_ + o] = f2bf(kf[q] - sig * mean);
}

// ---------------------------------------------------------------------------
// bf16 MFMA GEMM (m97 structure): D[m][n] = sum_k A[m][k]*Bt[n][k] + bias
// 128x128 tile, 4 waves each 64x64 (4x4 frags of 16x16), BK=32.
// ---------------------------------------------------------------------------
template<int BIAS_COL, bool OUT_BF16>
__global__ __launch_bounds__(256) void gemm_bt(const unsigned short* __restrict__ A,
                                               const unsigned short* __restrict__ Bt,
                                               const float* __restrict__ bias,
                                               void* __restrict__ Yv,
                                               int N,
                                               long long sA, long long sB, long long sY) {
    const int t = threadIdx.x;
    const int l = t & 63, w = t >> 6;
    const int m0 = blockIdx.y * 128, n0 = blockIdx.x * 128;
    const int b  = blockIdx.z;
    const unsigned short* Ab = A + (size_t)b * sA;
    const unsigned short* Bb = Bt + (size_t)b * sB;

    __shared__ __align__(16) unsigned short As[128 * 32];
    __shared__ __align__(16) unsigned short Bs[128 * 32];

    f32x4 acc[4][4] = {};
    const int wm = w >> 1, wn = w & 1;
    const int srow = t >> 2;
    const int skc  = (t & 3) * 8;

    for (int k0 = 0; k0 < 384; k0 += 32) {
        __builtin_amdgcn_global_load_lds(
            (gbl_void*)(Ab + (size_t)(m0 + srow) * 384 + k0 + skc),
            (lds_void*)(As + t * 8), 16, 0, 0);
        __builtin_amdgcn_global_load_lds(
            (gbl_void*)(Ab + (size_t)(m0 + 64 + srow) * 384 + k0 + skc),
            (lds_void*)(As + 2048 + t * 8), 16, 0, 0);
        __builtin_amdgcn_global_load_lds(
            (gbl_void*)(Bb + (size_t)(n0 + srow) * 384 + k0 + skc),
            (lds_void*)(Bs + t * 8), 16, 0, 0);
        __builtin_amdgcn_global_load_lds(
            (gbl_void*)(Bb + (size_t)(n0 + 64 + srow) * 384 + k0 + skc),
            (lds_void*)(Bs + 2048 + t * 8), 16, 0, 0);
        __syncthreads();

        const int lr = l & 15, lk = (l >> 4) * 8;
        bf16x8 af[4], bfr[4];
#pragma unroll
        for (int f = 0; f < 4; ++f)
            af[f] = *reinterpret_cast<const bf16x8*>(&As[(wm * 64 + f * 16 + lr) * 32 + lk]);
#pragma unroll
        for (int f = 0; f < 4; ++f)
            bfr[f] = *reinterpret_cast<const bf16x8*>(&Bs[(wn * 64 + f * 16 + lr) * 32 + lk]);
#pragma unroll
        for (int fm = 0; fm < 4; ++fm)
#pragma unroll
            for (int fn = 0; fn < 4; ++fn)
                acc[fm][fn] = __builtin_amdgcn_mfma_f32_16x16x32_bf16(af[fm], bfr[fn], acc[fm][fn], 0, 0, 0);
        __syncthreads();
    }

    const int lr = l & 15, lg = (l >> 4) * 4;
#pragma unroll
    for (int fm = 0; fm < 4; ++fm) {
        const int row = m0 + wm * 64 + fm * 16 + lg;
#pragma unroll
        for (int fn = 0; fn < 4; ++fn) {
            const int col = n0 + wn * 64 + fn * 16 + lr;
            const float cb = BIAS_COL ? bias[col] : 0.f;
#pragma unroll
            for (int r = 0; r < 4; ++r) {
                const float v = acc[fm][fn][r] + (BIAS_COL ? cb : bias[row + r]);
                if (OUT_BF16)
                    ((unsigned short*)Yv)[(size_t)b * sY + (size_t)(row + r) * N + col] = f2bf(v);
                else
                    ((float*)Yv)[(size_t)b * sY + (size_t)(row + r) * N + col] = v;
            }
        }
    }
}

// ---------------------------------------------------------------------------
// depthwise dynamic 3x3 (channel-last), one thread = one pixel x 8 channels.
// grid 6912 blocks x 256 threads.
// ---------------------------------------------------------------------------
__global__ __launch_bounds__(256) void dwT_kernel(const unsigned short* __restrict__ vT,
                                                  const unsigned short* __restrict__ kT,
                                                  unsigned short* __restrict__ oT) {
    int u = blockIdx.x * 256 + threadIdx.x;
    const int cg = u % 48;  u /= 48;
    const int p  = u % HW_;
    const int b  = u / HW_;
    const int h = p / W_, w = p % W_;
    const int c0 = cg * 8;
    const size_t base = (size_t)b * HW_ * C_;

    // kernels: keep as bf16 bits (low VGPR), convert at use
    u16x8 kv[9];
#pragma unroll
    for (int q = 0; q < 9; ++q)
        kv[q] = *(const u16x8*)&kT[((size_t)b * 9 + q) * C_ + c0];

    float acc[8] = {};
#pragma unroll
    for (int di = 0; di < 3; ++di) {
        const int hh = h + di - 1;
        if (hh < 0 || hh >= H_) continue;
#pragma unroll
        for (int dj = 0; dj < 3; ++dj) {
            const int wn = w + dj - 1;
            if (wn < 0 || wn >= W_) continue;
            const u16x8 v = *(const u16x8*)&vT[base + (size_t)(hh * W_ + wn) * C_ + c0];
            const int q = di * 3 + dj;
#pragma unroll
            for (int e = 0; e < 8; ++e)
                acc[e] = fmaf(bf2f(v[e]), bf2f(kv[q][e]), acc[e]);
        }
    }
    u16x8 o;
#pragma unroll
    for (int e = 0; e < 8; ++e) o[e] = f2bf(acc[e]);
    *(u16x8*)&oT[base + (size_t)p * C_ + c0] = o;
}

// ---------------------------------------------------------------------------
extern "C" void kernel_launch(void* const* d_in, const int* in_sizes, int n_in,
                              void* d_out, int out_size, void* d_ws, size_t ws_size,
                              hipStream_t stream) {
    const float* x  = (const float*)d_in[0];
    const float* Wq = (const float*)d_in[1];
    const float* bq = (const float*)d_in[2];
    const float* Wk = (const float*)d_in[3];
    const float* bk = (const float*)d_in[4];
    const float* Wv = (const float*)d_in[5];
    const float* bv = (const float*)d_in[6];
    const float* Wg = (const float*)d_in[7];
    const float* bg = (const float*)d_in[8];
    const float* Wp = (const float*)d_in[9];
    const float* bp = (const float*)d_in[10];
    float* out = (float*)d_out;

    char* ws = (char*)d_ws;
    const size_t bhwc2 = (size_t)B_ * HW_ * C_ * 2;          // 28,311,552 B
    unsigned short* xT     = (unsigned short*)ws;             // reused as out2T
    unsigned short* valueT = (unsigned short*)(ws + bhwc2);
    unsigned short* Wvb    = (unsigned short*)(ws + 2 * bhwc2);
    unsigned short* Wpb    = (unsigned short*)(ws + 2 * bhwc2 + 294912);
    float*          px     = (float*)(ws + 2 * bhwc2 + 2 * 294912);
    unsigned short* kernT  = (unsigned short*)(ws + 2 * bhwc2 + 2 * 294912 + 221184);
    unsigned short* out2T  = xT;   // xT dead after GEMM1

    castw_kernel<<<144, 256, 0, stream>>>(Wv, Wvb, C_ * C_);
    castw_kernel<<<144, 256, 0, stream>>>(Wp, Wpb, C_ * C_);
    tcast_kernel<<<dim3(HW_ / 64, C_ / 64, B_), 256, 0, stream>>>(x, xT);
    poolT_kernel<<<dim3(9, C_ / 64, B_), 256, 0, stream>>>(xT, px);
    small_kernel<<<dim3(3, B_), 128, 0, stream>>>(px, Wq, bq, Wk, bk, Wg, bg, kernT);

    // valueT[(b.p)][c] = xT[(b.p)][:] . Wv[c][:] + bv[c]  — batch folded into M
    gemm_bt<1, true><<<dim3(C_ / 128, (B_ * HW_) / 128, 1), 256, 0, stream>>>(
        xT, Wvb, bv, (void*)valueT, C_, 0LL, 0LL, 0LL);

    dwT_kernel<<<dim3((B_ * HW_ * (C_ / 8)) / 256), 256, 0, stream>>>(valueT, kernT, out2T);

    // out[b][c][p] = Wp[c][:] . out2T[b][p][:] + bp[c]
    gemm_bt<0, false><<<dim3(HW_ / 128, C_ / 128, B_), 256, 0, stream>>>(
        Wpb, out2T, bp, (void*)out, HW_,
        0LL, (long long)HW_ * C_, (long long)C_ * HW_);
}

// Round 4
// 125.488 us; speedup vs baseline: 2.9688x; 1.0984x over previous
//
#include <hip/hip_runtime.h>
#include <cstdint>
#include <cstddef>

// Problem constants
#define B_  16
#define C_  384
#define H_  48
#define W_  48
#define HW_ 2304        // 48*48

typedef __bf16 bf16x8 __attribute__((ext_vector_type(8)));
typedef float  f32x4  __attribute__((ext_vector_type(4)));
typedef unsigned short u16x8 __attribute__((ext_vector_type(8)));

typedef __attribute__((address_space(3))) void       lds_void;
typedef const __attribute__((address_space(1))) void gbl_void;

__device__ __forceinline__ unsigned short f2bf(float f) {
    union { float f; unsigned int u; } v; v.f = f;
    unsigned int r = v.u + 0x7fffu + ((v.u >> 16) & 1u);   // RNE
    return (unsigned short)(r >> 16);
}
__device__ __forceinline__ float bf2f(unsigned short u) {
    union { unsigned int u; float f; } v; v.u = ((unsigned int)u) << 16;
    return v.f;
}

// ---------------------------------------------------------------------------
// cast both weight matrices fp32 -> bf16 in one launch.
// grid 288: blocks 0..143 -> Wv, 144..287 -> Wp.  1024 elems/block.
// ---------------------------------------------------------------------------
__global__ void castw2_kernel(const float* __restrict__ wv, unsigned short* __restrict__ dv,
                              const float* __restrict__ wp, unsigned short* __restrict__ dp) {
    const int blk = blockIdx.x;
    const float* s = (blk < 144) ? wv : wp;
    unsigned short* d = (blk < 144) ? dv : dp;
    const int i = ((blk < 144 ? blk : blk - 144) * 256 + threadIdx.x) * 4;
    const float4 v = *(const float4*)&s[i];
    ushort4 o; o.x = f2bf(v.x); o.y = f2bf(v.y); o.z = f2bf(v.z); o.w = f2bf(v.w);
    *(ushort4*)&d[i] = o;
}

// ---------------------------------------------------------------------------
// transpose-cast: x[b][c][p] fp32 -> xT[b][p][c] bf16.  64x64 tiles via LDS.
// grid (36, 6, 16), block 256.
// ---------------------------------------------------------------------------
__global__ __launch_bounds__(256) void tcast_kernel(const float* __restrict__ x,
                                                    unsigned short* __restrict__ xT) {
    __shared__ unsigned short tile[64][68];   // [p][c], padded
    const int t  = threadIdx.x;
    const int b  = blockIdx.z;
    const int p0 = blockIdx.x * 64, c0 = blockIdx.y * 64;
    const float* xb = x + ((size_t)b * C_ + c0) * HW_ + p0;

#pragma unroll
    for (int pass = 0; pass < 4; ++pass) {
        const int cr = pass * 16 + (t >> 4);
        const int pc = (t & 15) * 4;
        const float4 v = *(const float4*)&xb[(size_t)cr * HW_ + pc];
        tile[pc + 0][cr] = f2bf(v.x); tile[pc + 1][cr] = f2bf(v.y);
        tile[pc + 2][cr] = f2bf(v.z); tile[pc + 3][cr] = f2bf(v.w);
    }
    __syncthreads();
    unsigned short* xTb = xT + ((size_t)b * HW_ + p0) * C_ + c0;
#pragma unroll
    for (int pass = 0; pass < 4; ++pass) {
        const int pr = pass * 16 + (t >> 4);
        const int cc = (t & 15) * 4;
        *(ushort4*)&xTb[(size_t)pr * C_ + cc] = *(const ushort4*)&tile[pr][cc];
    }
}

// ---------------------------------------------------------------------------
// poolT: 3x3 adaptive avg pool from xT (bf16, channel-last).
// px[b][c][r].  grid (9, 6, 16), block 256.
// ---------------------------------------------------------------------------
__global__ __launch_bounds__(256) void poolT_kernel(const unsigned short* __restrict__ xT,
                                                    float* __restrict__ px) {
    const int r  = blockIdx.x;
    const int c0 = blockIdx.y * 64;
    const int b  = blockIdx.z;
    const int t  = threadIdx.x;
    const int wv = t >> 6;
    const int l  = t & 63;
    const int i  = l >> 3;
    const int cg = l & 7;
    const int ri = r / 3, rj = r % 3;
    const int cbase = c0 + cg * 8;

    __shared__ float s[4][64];

    float acc[8] = {};
#pragma unroll
    for (int k = 0; k < 8; ++k) {
        const int pix = wv * 64 + i + k * 8;
        const int h = ri * 16 + (pix >> 4), w = rj * 16 + (pix & 15);
        const u16x8 v = *(const u16x8*)&xT[((size_t)b * HW_ + h * W_ + w) * C_ + cbase];
#pragma unroll
        for (int e = 0; e < 8; ++e) acc[e] += bf2f(v[e]);
    }
#pragma unroll
    for (int m = 8; m <= 32; m <<= 1)
#pragma unroll
        for (int e = 0; e < 8; ++e) acc[e] += __shfl_xor(acc[e], m, 64);
    if (i == 0)
#pragma unroll
        for (int e = 0; e < 8; ++e) s[wv][cg * 8 + e] = acc[e];
    __syncthreads();
    if (t < 64) {
        const float tot = s[0][t] + s[1][t] + s[2][t] + s[3][t];
        px[((size_t)b * C_ + c0 + t) * 9 + r] = tot * (1.f / 256.f);
    }
}

// ---------------------------------------------------------------------------
// small projections -> kernT[b][q][c] bf16.
// ---------------------------------------------------------------------------
__global__ void small_kernel(const float* __restrict__ px,
                             const float* __restrict__ Wq, const float* __restrict__ bq,
                             const float* __restrict__ Wk, const float* __restrict__ bk,
                             const float* __restrict__ Wg, const float* __restrict__ bg,
                             unsigned short* __restrict__ kernT) {
    const int b = blockIdx.y;
    const int o = blockIdx.x * 128 + threadIdx.x;

    __shared__ float px_l[C_ * 9];
    __shared__ float emb_l[C_];
    __shared__ float wg_l[81];
    __shared__ float bg_l[9];

    for (int idx = threadIdx.x; idx < C_ * 9; idx += 128) px_l[idx] = px[(size_t)b * C_ * 9 + idx];
    if (threadIdx.x < 81) wg_l[threadIdx.x] = Wg[threadIdx.x];
    if (threadIdx.x < 9)  bg_l[threadIdx.x] = bg[threadIdx.x];
    __syncthreads();
    for (int idx = threadIdx.x; idx < C_; idx += 128) {
        float s0 = 0.f;
#pragma unroll
        for (int p = 0; p < 9; ++p) s0 += px_l[idx * 9 + p];
        emb_l[idx] = s0 * (1.f / 9.f);
    }
    __syncthreads();

    float accq[9];
#pragma unroll
    for (int p = 0; p < 9; ++p) accq[p] = bq[o];
    float acck = bk[o];
    const float* wq_row = Wq + (size_t)o * C_;
    const float* wk_row = Wk + (size_t)o * C_;
    for (int i = 0; i < C_; ++i) {
        const float w = wq_row[i];
#pragma unroll
        for (int p = 0; p < 9; ++p) accq[p] = fmaf(w, px_l[i * 9 + p], accq[p]);
        acck = fmaf(wk_row[i], emb_l[i], acck);
    }

    float kf[9], mean = 0.f;
#pragma unroll
    for (int q = 0; q < 9; ++q) {
        float a = bg_l[q];
#pragma unroll
        for (int p = 0; p < 9; ++p) a = fmaf(accq[p], wg_l[q * 9 + p], a);
        kf[q] = a; mean += a;
    }
    mean *= (1.f / 9.f);
    const float sig = 1.f / (1.f + expf(-acck));
#pragma unroll
    for (int q = 0; q < 9; ++q)
        kernT[((size_t)b * 9 + q) * C_ + o] = f2bf(kf[q] - sig * mean);
}

// ---------------------------------------------------------------------------
// bf16 MFMA GEMM, BK=64, XOR-swizzled LDS (pre-swizzled global source,
// linear global_load_lds dest, swizzled ds_read), XCD-chunked 1-D grid.
// D[m][n] = sum_k A[m][k]*Bt[n][k] + bias.  A,Bt row-major K=384.
// 128x128 tile, 4 waves each 64x64 (4x4 frags of 16x16x32), 6 K-steps.
// BMAJOR=0: small-B (tile order: ntile fastest within chunk) — for gemm1.
// BMAJOR=1: small-A (mtile fastest) — for gemm2.
// ---------------------------------------------------------------------------
template<int BIAS_COL, bool OUT_BF16, int BMAJOR>
__global__ __launch_bounds__(256) void gemm_bt(const unsigned short* __restrict__ A,
                                               const unsigned short* __restrict__ Bt,
                                               const float* __restrict__ bias,
                                               void* __restrict__ Yv,
                                               int N, int nMt, int nNt, int perB,
                                               long long sA, long long sB, long long sY) {
    // bijective XCD swizzle (gridDim.x % 8 == 0)
    const int q8  = gridDim.x >> 3;
    const int swz = (blockIdx.x & 7) * q8 + (blockIdx.x >> 3);
    const int b   = swz / perB;
    const int r   = swz % perB;
    const int mtile = BMAJOR ? (r % nMt) : (r / nNt);
    const int ntile = BMAJOR ? (r / nMt) : (r % nNt);
    const int m0 = mtile * 128, n0 = ntile * 128;

    const int t = threadIdx.x;
    const int l = t & 63, w = t >> 6;
    const unsigned short* Ab = A + (size_t)b * sA;
    const unsigned short* Bb = Bt + (size_t)b * sB;

    __shared__ __align__(16) unsigned short As[128 * 64];
    __shared__ __align__(16) unsigned short Bs[128 * 64];

    f32x4 acc[4][4] = {};
    const int wm = w >> 1, wn = w & 1;

    // staging decomposition: thread t -> rows {32j + (t>>3)}, k-chunk slot t&7.
    // LDS dest linear; global source k-chunk = slot ^ (row&7)  (T2 swizzle).
    const int srow = t >> 3;                     // 0..31
    const int skc  = t & 7;                      // LDS k-chunk slot
    const int gkc  = skc ^ (srow & 7);           // swizzled global k-chunk

    const int lr = l & 15;                       // frag row within 16
    const int kq = l >> 4;                       // k-quarter 0..3
    const int xorv = lr & 7;                     // read-side swizzle

    for (int k0 = 0; k0 < 384; k0 += 64) {
#pragma unroll
        for (int j = 0; j < 4; ++j)
            __builtin_amdgcn_global_load_lds(
                (gbl_void*)(Ab + (size_t)(m0 + 32 * j + srow) * 384 + k0 + gkc * 8),
                (lds_void*)(As + (32 * j + srow) * 64 + skc * 8), 16, 0, 0);
#pragma unroll
        for (int j = 0; j < 4; ++j)
            __builtin_amdgcn_global_load_lds(
                (gbl_void*)(Bb + (size_t)(n0 + 32 * j + srow) * 384 + k0 + gkc * 8),
                (lds_void*)(Bs + (32 * j + srow) * 64 + skc * 8), 16, 0, 0);
        __syncthreads();

#pragma unroll
        for (int sub = 0; sub < 2; ++sub) {
            const int kc = sub * 4 + kq;                 // global k-chunk wanted
            const int ko = (kc ^ xorv) * 8;              // swizzled LDS offset
            bf16x8 af[4], bfr[4];
#pragma unroll
            for (int f = 0; f < 4; ++f)
                af[f] = *reinterpret_cast<const bf16x8*>(&As[(wm * 64 + f * 16 + lr) * 64 + ko]);
#pragma unroll
            for (int f = 0; f < 4; ++f)
                bfr[f] = *reinterpret_cast<const bf16x8*>(&Bs[(wn * 64 + f * 16 + lr) * 64 + ko]);
#pragma unroll
            for (int fm = 0; fm < 4; ++fm)
#pragma unroll
                for (int fn = 0; fn < 4; ++fn)
                    acc[fm][fn] = __builtin_amdgcn_mfma_f32_16x16x32_bf16(af[fm], bfr[fn], acc[fm][fn], 0, 0, 0);
        }
        __syncthreads();
    }

    const int lg = (l >> 4) * 4;
#pragma unroll
    for (int fm = 0; fm < 4; ++fm) {
        const int row = m0 + wm * 64 + fm * 16 + lg;
#pragma unroll
        for (int fn = 0; fn < 4; ++fn) {
            const int col = n0 + wn * 64 + fn * 16 + lr;
            const float cb = BIAS_COL ? bias[col] : 0.f;
#pragma unroll
            for (int rr = 0; rr < 4; ++rr) {
                const float v = acc[fm][fn][rr] + (BIAS_COL ? cb : bias[row + rr]);
                if (OUT_BF16)
                    ((unsigned short*)Yv)[(size_t)b * sY + (size_t)(row + rr) * N + col] = f2bf(v);
                else
                    ((float*)Yv)[(size_t)b * sY + (size_t)(row + rr) * N + col] = v;
            }
        }
    }
}

// ---------------------------------------------------------------------------
// depthwise dynamic 3x3 (channel-last), one thread = one pixel x 8 channels.
// ---------------------------------------------------------------------------
__global__ __launch_bounds__(256) void dwT_kernel(const unsigned short* __restrict__ vT,
                                                  const unsigned short* __restrict__ kT,
                                                  unsigned short* __restrict__ oT) {
    int u = blockIdx.x * 256 + threadIdx.x;
    const int cg = u % 48;  u /= 48;
    const int p  = u % HW_;
    const int b  = u / HW_;
    const int h = p / W_, w = p % W_;
    const int c0 = cg * 8;
    const size_t base = (size_t)b * HW_ * C_;

    u16x8 kv[9];
#pragma unroll
    for (int q = 0; q < 9; ++q)
        kv[q] = *(const u16x8*)&kT[((size_t)b * 9 + q) * C_ + c0];

    float acc[8] = {};
#pragma unroll
    for (int di = 0; di < 3; ++di) {
        const int hh = h + di - 1;
        if (hh < 0 || hh >= H_) continue;
#pragma unroll
        for (int dj = 0; dj < 3; ++dj) {
            const int wn = w + dj - 1;
            if (wn < 0 || wn >= W_) continue;
            const u16x8 v = *(const u16x8*)&vT[base + (size_t)(hh * W_ + wn) * C_ + c0];
            const int q = di * 3 + dj;
#pragma unroll
            for (int e = 0; e < 8; ++e)
                acc[e] = fmaf(bf2f(v[e]), bf2f(kv[q][e]), acc[e]);
        }
    }
    u16x8 o;
#pragma unroll
    for (int e = 0; e < 8; ++e) o[e] = f2bf(acc[e]);
    *(u16x8*)&oT[base + (size_t)p * C_ + c0] = o;
}

// ---------------------------------------------------------------------------
extern "C" void kernel_launch(void* const* d_in, const int* in_sizes, int n_in,
                              void* d_out, int out_size, void* d_ws, size_t ws_size,
                              hipStream_t stream) {
    const float* x  = (const float*)d_in[0];
    const float* Wq = (const float*)d_in[1];
    const float* bq = (const float*)d_in[2];
    const float* Wk = (const float*)d_in[3];
    const float* bk = (const float*)d_in[4];
    const float* Wv = (const float*)d_in[5];
    const float* bv = (const float*)d_in[6];
    const float* Wg = (const float*)d_in[7];
    const float* bg = (const float*)d_in[8];
    const float* Wp = (const float*)d_in[9];
    const float* bp = (const float*)d_in[10];
    float* out = (float*)d_out;

    char* ws = (char*)d_ws;
    const size_t bhwc2 = (size_t)B_ * HW_ * C_ * 2;          // 28,311,552 B
    unsigned short* xT     = (unsigned short*)ws;             // reused as out2T
    unsigned short* valueT = (unsigned short*)(ws + bhwc2);
    unsigned short* Wvb    = (unsigned short*)(ws + 2 * bhwc2);
    unsigned short* Wpb    = (unsigned short*)(ws + 2 * bhwc2 + 294912);
    float*          px     = (float*)(ws + 2 * bhwc2 + 2 * 294912);
    unsigned short* kernT  = (unsigned short*)(ws + 2 * bhwc2 + 2 * 294912 + 221184);
    unsigned short* out2T  = xT;   // xT dead after GEMM1

    castw2_kernel<<<288, 256, 0, stream>>>(Wv, Wvb, Wp, Wpb);
    tcast_kernel<<<dim3(HW_ / 64, C_ / 64, B_), 256, 0, stream>>>(x, xT);
    poolT_kernel<<<dim3(9, C_ / 64, B_), 256, 0, stream>>>(xT, px);
    small_kernel<<<dim3(3, B_), 128, 0, stream>>>(px, Wq, bq, Wk, bk, Wg, bg, kernT);

    // GEMM1: valueT[(b.p)][c] = xT[(b.p)][:] . Wv[c][:] + bv[c]
    // M = 36864 (288 tiles), N = 384 (3 tiles), batch folded: perB = 864.
    gemm_bt<1, true, 0><<<864, 256, 0, stream>>>(
        xT, Wvb, bv, (void*)valueT, C_, 288, 3, 864, 0LL, 0LL, 0LL);

    dwT_kernel<<<dim3((B_ * HW_ * (C_ / 8)) / 256), 256, 0, stream>>>(valueT, kernT, out2T);

    // GEMM2: out[b][c][p] = Wp[c][:] . out2T[b][p][:] + bp[c]
    // per-batch M = 384 (3 tiles), N = 2304 (18 tiles), perB = 54.
    gemm_bt<0, false, 1><<<864, 256, 0, stream>>>(
        Wpb, out2T, bp, (void*)out, HW_, 3, 18, 54,
        0LL, (long long)HW_ * C_, (long long)C_ * HW_);
}